// Round 7
// baseline (64.099 us; speedup 1.0000x reference)
//
#include <hip/hip_runtime.h>
#include <hip/hip_bf16.h>
#include <math.h>

#define B_DIM 4096
#define CIN   2048
#define COUT  2048

typedef _Float16 f16x8 __attribute__((ext_vector_type(8)));
typedef _Float16 f16x4 __attribute__((ext_vector_type(4)));
typedef float    f32x4 __attribute__((ext_vector_type(4)));
typedef float    f32x16 __attribute__((ext_vector_type(16)));

__device__ inline float wave_reduce_sum(float v) {
#pragma unroll
    for (int off = 32; off > 0; off >>= 1)
        v += __shfl_down(v, off, 64);
    return v;
}
__device__ inline float wave_reduce_max(float v) {
#pragma unroll
    for (int off = 32; off > 0; off >>= 1)
        v = fmaxf(v, __shfl_down(v, off, 64));
    return v;
}

// ---------------------------------------------------------------------------
// Kernel A (fused): blocks [0,4096)   : quantize x -> XQ (f16), term_x
//                   blocks [4096,4352): partial max|weight| -> pmax[256]
//                   block  4352       : tables s[i]=sin(phi)*(d0+d1), dd[i]=d0-d1
// ---------------------------------------------------------------------------
#define NMAXBLK 256
__global__ void prep_a_kernel(const float* __restrict__ x,
                              const float* __restrict__ weight,
                              const float* __restrict__ phases,
                              const float* __restrict__ disks,
                              _Float16* __restrict__ XQ,
                              float* __restrict__ term_x,
                              float* __restrict__ pmax,
                              float* __restrict__ s_tab,
                              float* __restrict__ dd_tab) {
    __shared__ float red[4];
    const int blk = blockIdx.x;
    const int tid = threadIdx.x;

    if (blk < B_DIM) {
        const f32x4* x4  = (const f32x4*)(x + (size_t)blk * CIN);
        const f32x4* dk  = (const f32x4*)disks;   // [CIN][2] interleaved
        f16x4* xq4 = (f16x4*)(XQ + (size_t)blk * CIN);
        float sum = 0.f;
        for (int g = tid; g < CIN / 4; g += 256) {
            f32x4 v   = x4[g];
            f32x4 dv0 = dk[2 * g];
            f32x4 dv1 = dk[2 * g + 1];
            float dd0 = dv0[0] - dv0[1], dd1 = dv0[2] - dv0[3];
            float dd2 = dv1[0] - dv1[1], dd3 = dv1[2] - dv1[3];
            f16x4 h;
            float q0 = rintf(fminf(fmaxf(v[0], 0.f), 1.f) * 255.f) * (1.f / 255.f);
            float q1 = rintf(fminf(fmaxf(v[1], 0.f), 1.f) * 255.f) * (1.f / 255.f);
            float q2 = rintf(fminf(fmaxf(v[2], 0.f), 1.f) * 255.f) * (1.f / 255.f);
            float q3 = rintf(fminf(fmaxf(v[3], 0.f), 1.f) * 255.f) * (1.f / 255.f);
            h[0] = (_Float16)q0; h[1] = (_Float16)q1;
            h[2] = (_Float16)q2; h[3] = (_Float16)q3;
            xq4[g] = h;
            sum += q0 * q0 * dd0 + q1 * q1 * dd1 + q2 * q2 * dd2 + q3 * q3 * dd3;
        }
        sum = wave_reduce_sum(sum);
        if ((tid & 63) == 0) red[tid >> 6] = sum;
        __syncthreads();
        if (tid == 0)
            term_x[blk] = 0.25f * (red[0] + red[1] + red[2] + red[3]);
    } else if (blk < B_DIM + NMAXBLK) {
        const int mb = blk - B_DIM;
        const size_t n4 = (size_t)COUT * CIN / 4;
        const f32x4* w4 = (const f32x4*)weight;
        float m = 0.f;
        for (size_t i = (size_t)mb * 256 + tid; i < n4; i += (size_t)NMAXBLK * 256) {
            f32x4 v = w4[i];
            m = fmaxf(m, fmaxf(fmaxf(fabsf(v[0]), fabsf(v[1])),
                               fmaxf(fabsf(v[2]), fabsf(v[3]))));
        }
        m = wave_reduce_max(m);
        if ((tid & 63) == 0) red[tid >> 6] = m;
        __syncthreads();
        if (tid == 0)
            pmax[mb] = fmaxf(fmaxf(red[0], red[1]), fmaxf(red[2], red[3]));
    } else {
        for (int i = tid; i < CIN; i += 256) {
            float d0 = disks[2 * i], d1 = disks[2 * i + 1];
            s_tab[i]  = sinf(phases[i]) * (d0 + d1);
            dd_tab[i] = d0 - d1;
        }
    }
}

// ---------------------------------------------------------------------------
// Kernel B: per-row weight quantize -> V = wq * s (f16), term_w
// ---------------------------------------------------------------------------
__global__ void prep_b_kernel(const float* __restrict__ weight,
                              const float* __restrict__ pmax,
                              const float* __restrict__ s_tab,
                              const float* __restrict__ dd_tab,
                              _Float16* __restrict__ V,
                              float* __restrict__ term_w) {
    __shared__ float red[4];
    __shared__ float bmax;
    const int tid = threadIdx.x;

    float m = pmax[tid];
    m = wave_reduce_max(m);
    if ((tid & 63) == 0) red[tid >> 6] = m;
    __syncthreads();
    if (tid == 0)
        bmax = tanhf(fmaxf(fmaxf(red[0], red[1]), fmaxf(red[2], red[3])));
    __syncthreads();
    const float inv2m = 0.5f / bmax;             // max|tanh(W)| = tanh(max|W|)

    const int o = blockIdx.x;
    const f32x4* w4  = (const f32x4*)(weight + (size_t)o * CIN);
    const f32x4* s4  = (const f32x4*)s_tab;
    const f32x4* dd4 = (const f32x4*)dd_tab;
    f16x4* v4 = (f16x4*)(V + (size_t)o * CIN);
    float sum = 0.f;
    for (int g = tid; g < CIN / 4; g += 256) {
        f32x4 wv = w4[g], sv = s4[g], ddv = dd4[g];
        f16x4 h;
#pragma unroll
        for (int j = 0; j < 4; ++j) {
            float t  = tanhf(wv[j]);
            float wq = rintf((t * inv2m + 0.5f) * 255.f) * (1.f / 255.f);
            sum += wq * wq * ddv[j];
            h[j] = (_Float16)(wq * sv[j]);
        }
        v4[g] = h;
    }
    sum = wave_reduce_sum(sum);
    __syncthreads();
    if ((tid & 63) == 0) red[tid >> 6] = sum;
    __syncthreads();
    if (tid == 0)
        term_w[o] = 0.25f * (red[0] + red[1] + red[2] + red[3]);
}

// ---------------------------------------------------------------------------
// Kernel C: GEMM  C[b][o] = 0.5*sum_k XQ[b][k]*V[o][k] + term_x[b] + term_w[o]
// 128x128 tile, BK=64, 4 waves (2Mx2N, 64x64/wave as 2x2 of 32x32x16 MFMA).
// Double-buffered LDS (64 KB -> 2 blocks/CU), STAGE(t+1) before COMPUTE(t),
// one vmcnt(0)+barrier per K-tile (drain covered by sibling block).
// LDS swizzle (FIXED from r6): physical granule = logical ^ f(row),
//   f(row) = (row&7) ^ (((row>>4)&1)<<1).
// The row-bit-4 term separates quarter-wave groups {l,l+16,l+32,l+48} that
// the LDS pipe services together: for 32x32 fragment reads lanes l and l+16
// share logical granule AND row&7 (rows differ by 16), which in r6 collided
// 4-way (SQ_LDS_BANK_CONFLICT = 4 cyc x 2^20 reads). With bit4 folded in the
// quarter-group granules are {a, a^2, a^1, a^3} -> all distinct.
// XCD supertile swizzle kept (r6-verified: FETCH 69.7 -> 32.8 MB).
// ---------------------------------------------------------------------------
#define BM 128
#define BN 128
#define BK 64
#define NT (CIN / BK)   // 32

#define MEMFENCE asm volatile("" ::: "memory")
#define BARRIER() do { MEMFENCE; __builtin_amdgcn_s_barrier(); MEMFENCE; } while (0)
#define VMCNT0 asm volatile("s_waitcnt vmcnt(0)" ::: "memory")

__global__ __launch_bounds__(256, 2) void
gemm_kernel(const _Float16* __restrict__ A,   // [B_DIM][CIN]
            const _Float16* __restrict__ Bw,  // [COUT][CIN]
            const float* __restrict__ term_x, // pre*0.25
            const float* __restrict__ term_w, // pre*0.25
            float* __restrict__ C) {
    __shared__ __align__(16) _Float16 As[2][BM * BK];  // 2 x 16 KB
    __shared__ __align__(16) _Float16 Bs[2][BN * BK];  // 2 x 16 KB

    const int tid  = threadIdx.x;
    const int wave = tid >> 6;
    const int lane = tid & 63;

    // XCD-aware supertile swizzle: 512 blocks, xcd = wg&7; each XCD owns an
    // 8x8 tile rectangle -> A/B panel reuse in its private L2.
    const int wg  = blockIdx.x;
    const int xcd = wg & 7;
    const int idx = wg >> 3;                         // 0..63
    const int tile_m = (xcd >> 1) * 8 + (idx >> 3);  // 0..31
    const int tile_n = (xcd & 1) * 8 + (idx & 7);    // 0..15
    const int row0 = tile_m * BM;
    const int col0 = tile_n * BN;
    const int wr = wave >> 1;   // 0..1 (M)
    const int wc = wave & 1;    // 0..1 (N)

    f32x16 acc[2][2];
#pragma unroll
    for (int m = 0; m < 2; ++m)
#pragma unroll
        for (int n = 0; n < 2; ++n)
#pragma unroll
            for (int j = 0; j < 16; ++j)
                acc[m][n][j] = 0.f;

    // staging: chunk = 8 rows x 64 f16 = 1 KB = one global_load_lds per wave.
    // HW writes lane l at chunkbase + 16*l -> row = chunk*8 + (l>>3), phys
    // granule l&7. Source fetches logical granule (l&7) ^ f(row) where
    // f(row) = (row&7) ^ ((row>>4 & 1)<<1) = st_row ^ ((chunk>>1 & 1)<<1).
    const int st_row = lane >> 3;
    const int st_g   = lane & 7;
    const _Float16* Agp = A  + (size_t)row0 * CIN;
    const _Float16* Bgp = Bw + (size_t)col0 * CIN;

    // 32x32x16 fragment addressing: row = lane&31, k = (lane>>5)*8 + j.
    const int rl = lane & 31;
    const int hi = lane >> 5;            // 0/1
    const int h3 = lane & 7;
    const int q4 = (lane >> 4) & 1;      // row bit 4

    // loop-invariant LDS read offsets: logical granule g = s*2+hi of row r
    // lives at physical granule g ^ f(r); f(r) = h3 ^ (q4<<1)
    // (wr*64, m*32 are 0 mod 32 so don't affect row&7 or row bit 4).
    int offA[4][2], offB[4][2];
#pragma unroll
    for (int s = 0; s < 4; ++s)
#pragma unroll
        for (int m = 0; m < 2; ++m) {
            const int pg = ((s * 2 + hi) ^ h3 ^ (q4 << 1)) * 8;
            offA[s][m] = (wr * 64 + m * 32 + rl) * BK + pg;
            offB[s][m] = (wc * 64 + m * 32 + rl) * BK + pg;
        }

#define STAGE(buf, k0) do {                                                    \
    _Pragma("unroll")                                                          \
    for (int j = 0; j < 4; ++j) {                                              \
        const int chunk = wave + j * 4;     /* 16 chunks cover 128 rows */     \
        const int rr = chunk * 8 + st_row;                                     \
        const int sc = (st_g ^ st_row ^ (((chunk >> 1) & 1) << 1)) * 8;        \
        __builtin_amdgcn_global_load_lds(                                      \
            (const __attribute__((address_space(1))) void*)(Agp + (size_t)rr * CIN + (k0) + sc), \
            (__attribute__((address_space(3))) void*)(&As[buf][chunk * 512]),  \
            16, 0, 0);                                                         \
        __builtin_amdgcn_global_load_lds(                                      \
            (const __attribute__((address_space(1))) void*)(Bgp + (size_t)rr * CIN + (k0) + sc), \
            (__attribute__((address_space(3))) void*)(&Bs[buf][chunk * 512]),  \
            16, 0, 0);                                                         \
    } } while (0)

#define COMPUTE(buf) do {                                                      \
    _Pragma("unroll")                                                          \
    for (int s = 0; s < 4; ++s) {                                              \
        f16x8 af0 = *(const f16x8*)(&As[buf][offA[s][0]]);                     \
        f16x8 af1 = *(const f16x8*)(&As[buf][offA[s][1]]);                     \
        f16x8 bf0 = *(const f16x8*)(&Bs[buf][offB[s][0]]);                     \
        f16x8 bf1 = *(const f16x8*)(&Bs[buf][offB[s][1]]);                     \
        __builtin_amdgcn_s_setprio(1);                                         \
        acc[0][0] = __builtin_amdgcn_mfma_f32_32x32x16_f16(af0, bf0, acc[0][0], 0, 0, 0); \
        acc[0][1] = __builtin_amdgcn_mfma_f32_32x32x16_f16(af0, bf1, acc[0][1], 0, 0, 0); \
        acc[1][0] = __builtin_amdgcn_mfma_f32_32x32x16_f16(af1, bf0, acc[1][0], 0, 0, 0); \
        acc[1][1] = __builtin_amdgcn_mfma_f32_32x32x16_f16(af1, bf1, acc[1][1], 0, 0, 0); \
        __builtin_amdgcn_s_setprio(0);                                         \
    } } while (0)

    // prologue
    STAGE(0, 0);
    VMCNT0;
    BARRIER();

#pragma unroll 1
    for (int t = 0; t < NT; t += 2) {
        STAGE(1, (t + 1) * BK);           // prefetch overlaps compute
        COMPUTE(0);
        VMCNT0;                           // drain covered by sibling block
        BARRIER();
        if (t + 2 < NT) STAGE(0, (t + 2) * BK);
        COMPUTE(1);
        if (t + 2 < NT) { VMCNT0; BARRIER(); }
    }

    // epilogue: 32x32 C/D layout: col = lane&31,
    // row = (reg&3) + 8*(reg>>2) + 4*(lane>>5)
#pragma unroll
    for (int m = 0; m < 2; ++m)
#pragma unroll
        for (int n = 0; n < 2; ++n) {
            const int c = col0 + wc * 64 + n * 32 + rl;
            const float tw = term_w[c];
#pragma unroll
            for (int reg = 0; reg < 16; ++reg) {
                const int r = row0 + wr * 64 + m * 32 +
                              (reg & 3) + 8 * (reg >> 2) + 4 * hi;
                C[(size_t)r * COUT + c] = 0.5f * acc[m][n][reg] + term_x[r] + tw;
            }
        }
#undef STAGE
#undef COMPUTE
}

// ---------------------------------------------------------------- launcher
extern "C" void kernel_launch(void* const* d_in, const int* in_sizes, int n_in,
                              void* d_out, int out_size, void* d_ws, size_t ws_size,
                              hipStream_t stream) {
    const float* x      = (const float*)d_in[0];
    const float* weight = (const float*)d_in[1];
    const float* phases = (const float*)d_in[2];
    const float* disks  = (const float*)d_in[3];
    float* out = (float*)d_out;

    char* ws = (char*)d_ws;
    float* pmax   = (float*)(ws);                    // 1 KB
    float* s_tab  = (float*)(ws + 4096);             // 8 KB
    float* dd_tab = (float*)(ws + 16384);            // 8 KB
    float* term_w = (float*)(ws + 32768);            // 8 KB
    float* term_x = (float*)(ws + 49152);            // 16 KB
    _Float16* V   = (_Float16*)(ws + 65536);                               // 8 MB
    _Float16* XQ  = (_Float16*)(ws + 65536 + (size_t)COUT * CIN * 2);      // 16 MB

    prep_a_kernel<<<B_DIM + NMAXBLK + 1, 256, 0, stream>>>(
        x, weight, phases, disks, XQ, term_x, pmax, s_tab, dd_tab);
    prep_b_kernel<<<COUT, 256, 0, stream>>>(weight, pmax, s_tab, dd_tab, V, term_w);
    gemm_kernel<<<(B_DIM / BM) * (COUT / BN), 256, 0, stream>>>(XQ, V, term_x, term_w, out);
}

// Round 8
// 63.976 us; speedup vs baseline: 1.0019x; 1.0019x over previous
//
#include <hip/hip_runtime.h>
#include <hip/hip_bf16.h>
#include <math.h>

#define B_DIM 4096
#define CIN   2048
#define COUT  2048

typedef _Float16 f16x8 __attribute__((ext_vector_type(8)));
typedef _Float16 f16x4 __attribute__((ext_vector_type(4)));
typedef float    f32x4 __attribute__((ext_vector_type(4)));
typedef float    f32x16 __attribute__((ext_vector_type(16)));

__device__ inline float wave_reduce_sum(float v) {
#pragma unroll
    for (int off = 32; off > 0; off >>= 1)
        v += __shfl_down(v, off, 64);
    return v;
}
__device__ inline float wave_reduce_max(float v) {
#pragma unroll
    for (int off = 32; off > 0; off >>= 1)
        v = fmaxf(v, __shfl_down(v, off, 64));
    return v;
}

// ---------------------------------------------------------------------------
// Kernel A (fused): blocks [0,4096)   : quantize x -> XQ (f16), term_x
//                   blocks [4096,4352): partial max|weight| -> pmax[256]
//                   block  4352       : tables s[i]=sin(phi)*(d0+d1), dd[i]=d0-d1
// ---------------------------------------------------------------------------
#define NMAXBLK 256
__global__ void prep_a_kernel(const float* __restrict__ x,
                              const float* __restrict__ weight,
                              const float* __restrict__ phases,
                              const float* __restrict__ disks,
                              _Float16* __restrict__ XQ,
                              float* __restrict__ term_x,
                              float* __restrict__ pmax,
                              float* __restrict__ s_tab,
                              float* __restrict__ dd_tab) {
    __shared__ float red[4];
    const int blk = blockIdx.x;
    const int tid = threadIdx.x;

    if (blk < B_DIM) {
        const f32x4* x4  = (const f32x4*)(x + (size_t)blk * CIN);
        const f32x4* dk  = (const f32x4*)disks;   // [CIN][2] interleaved
        f16x4* xq4 = (f16x4*)(XQ + (size_t)blk * CIN);
        float sum = 0.f;
        for (int g = tid; g < CIN / 4; g += 256) {
            f32x4 v   = x4[g];
            f32x4 dv0 = dk[2 * g];
            f32x4 dv1 = dk[2 * g + 1];
            float dd0 = dv0[0] - dv0[1], dd1 = dv0[2] - dv0[3];
            float dd2 = dv1[0] - dv1[1], dd3 = dv1[2] - dv1[3];
            f16x4 h;
            float q0 = rintf(fminf(fmaxf(v[0], 0.f), 1.f) * 255.f) * (1.f / 255.f);
            float q1 = rintf(fminf(fmaxf(v[1], 0.f), 1.f) * 255.f) * (1.f / 255.f);
            float q2 = rintf(fminf(fmaxf(v[2], 0.f), 1.f) * 255.f) * (1.f / 255.f);
            float q3 = rintf(fminf(fmaxf(v[3], 0.f), 1.f) * 255.f) * (1.f / 255.f);
            h[0] = (_Float16)q0; h[1] = (_Float16)q1;
            h[2] = (_Float16)q2; h[3] = (_Float16)q3;
            xq4[g] = h;
            sum += q0 * q0 * dd0 + q1 * q1 * dd1 + q2 * q2 * dd2 + q3 * q3 * dd3;
        }
        sum = wave_reduce_sum(sum);
        if ((tid & 63) == 0) red[tid >> 6] = sum;
        __syncthreads();
        if (tid == 0)
            term_x[blk] = 0.25f * (red[0] + red[1] + red[2] + red[3]);
    } else if (blk < B_DIM + NMAXBLK) {
        const int mb = blk - B_DIM;
        const size_t n4 = (size_t)COUT * CIN / 4;
        const f32x4* w4 = (const f32x4*)weight;
        float m = 0.f;
        for (size_t i = (size_t)mb * 256 + tid; i < n4; i += (size_t)NMAXBLK * 256) {
            f32x4 v = w4[i];
            m = fmaxf(m, fmaxf(fmaxf(fabsf(v[0]), fabsf(v[1])),
                               fmaxf(fabsf(v[2]), fabsf(v[3]))));
        }
        m = wave_reduce_max(m);
        if ((tid & 63) == 0) red[tid >> 6] = m;
        __syncthreads();
        if (tid == 0)
            pmax[mb] = fmaxf(fmaxf(red[0], red[1]), fmaxf(red[2], red[3]));
    } else {
        for (int i = tid; i < CIN; i += 256) {
            float d0 = disks[2 * i], d1 = disks[2 * i + 1];
            s_tab[i]  = sinf(phases[i]) * (d0 + d1);
            dd_tab[i] = d0 - d1;
        }
    }
}

// ---------------------------------------------------------------------------
// Kernel B: per-row weight quantize -> V = wq * s (f16), term_w
// ---------------------------------------------------------------------------
__global__ void prep_b_kernel(const float* __restrict__ weight,
                              const float* __restrict__ pmax,
                              const float* __restrict__ s_tab,
                              const float* __restrict__ dd_tab,
                              _Float16* __restrict__ V,
                              float* __restrict__ term_w) {
    __shared__ float red[4];
    __shared__ float bmax;
    const int tid = threadIdx.x;

    float m = pmax[tid];
    m = wave_reduce_max(m);
    if ((tid & 63) == 0) red[tid >> 6] = m;
    __syncthreads();
    if (tid == 0)
        bmax = tanhf(fmaxf(fmaxf(red[0], red[1]), fmaxf(red[2], red[3])));
    __syncthreads();
    const float inv2m = 0.5f / bmax;             // max|tanh(W)| = tanh(max|W|)

    const int o = blockIdx.x;
    const f32x4* w4  = (const f32x4*)(weight + (size_t)o * CIN);
    const f32x4* s4  = (const f32x4*)s_tab;
    const f32x4* dd4 = (const f32x4*)dd_tab;
    f16x4* v4 = (f16x4*)(V + (size_t)o * CIN);
    float sum = 0.f;
    for (int g = tid; g < CIN / 4; g += 256) {
        f32x4 wv = w4[g], sv = s4[g], ddv = dd4[g];
        f16x4 h;
#pragma unroll
        for (int j = 0; j < 4; ++j) {
            float t  = tanhf(wv[j]);
            float wq = rintf((t * inv2m + 0.5f) * 255.f) * (1.f / 255.f);
            sum += wq * wq * ddv[j];
            h[j] = (_Float16)(wq * sv[j]);
        }
        v4[g] = h;
    }
    sum = wave_reduce_sum(sum);
    __syncthreads();
    if ((tid & 63) == 0) red[tid >> 6] = sum;
    __syncthreads();
    if (tid == 0)
        term_w[o] = 0.25f * (red[0] + red[1] + red[2] + red[3]);
}

// ---------------------------------------------------------------------------
// Kernel C: GEMM  C[b][o] = 0.5*sum_k XQ[b][k]*V[o][k] + term_x[b] + term_w[o]
// 128x128 tile, BK=64, 4 waves (2Mx2N, 64x64/wave as 2x2 of 32x32x16 MFMA).
// Double-buffered LDS (64 KB -> 2 blocks/CU), STAGE(t+1) before COMPUTE(t),
// one vmcnt(0)+barrier per K-tile (drain covered by sibling block).
// LDS swizzle (FIXED from r6): physical granule = logical ^ f(row),
//   f(row) = (row&7) ^ (((row>>4)&1)<<1).
// The row-bit-4 term separates quarter-wave groups {l,l+16,l+32,l+48} that
// the LDS pipe services together: for 32x32 fragment reads lanes l and l+16
// share logical granule AND row&7 (rows differ by 16), which in r6 collided
// 4-way (SQ_LDS_BANK_CONFLICT = 4 cyc x 2^20 reads). With bit4 folded in the
// quarter-group granules are {a, a^2, a^1, a^3} -> all distinct.
// XCD supertile swizzle kept (r6-verified: FETCH 69.7 -> 32.8 MB).
// ---------------------------------------------------------------------------
#define BM 128
#define BN 128
#define BK 64
#define NT (CIN / BK)   // 32

#define MEMFENCE asm volatile("" ::: "memory")
#define BARRIER() do { MEMFENCE; __builtin_amdgcn_s_barrier(); MEMFENCE; } while (0)
#define VMCNT0 asm volatile("s_waitcnt vmcnt(0)" ::: "memory")

__global__ __launch_bounds__(256, 2) void
gemm_kernel(const _Float16* __restrict__ A,   // [B_DIM][CIN]
            const _Float16* __restrict__ Bw,  // [COUT][CIN]
            const float* __restrict__ term_x, // pre*0.25
            const float* __restrict__ term_w, // pre*0.25
            float* __restrict__ C) {
    __shared__ __align__(16) _Float16 As[2][BM * BK];  // 2 x 16 KB
    __shared__ __align__(16) _Float16 Bs[2][BN * BK];  // 2 x 16 KB

    const int tid  = threadIdx.x;
    const int wave = tid >> 6;
    const int lane = tid & 63;

    // XCD-aware supertile swizzle: 512 blocks, xcd = wg&7; each XCD owns an
    // 8x8 tile rectangle -> A/B panel reuse in its private L2.
    const int wg  = blockIdx.x;
    const int xcd = wg & 7;
    const int idx = wg >> 3;                         // 0..63
    const int tile_m = (xcd >> 1) * 8 + (idx >> 3);  // 0..31
    const int tile_n = (xcd & 1) * 8 + (idx & 7);    // 0..15
    const int row0 = tile_m * BM;
    const int col0 = tile_n * BN;
    const int wr = wave >> 1;   // 0..1 (M)
    const int wc = wave & 1;    // 0..1 (N)

    f32x16 acc[2][2];
#pragma unroll
    for (int m = 0; m < 2; ++m)
#pragma unroll
        for (int n = 0; n < 2; ++n)
#pragma unroll
            for (int j = 0; j < 16; ++j)
                acc[m][n][j] = 0.f;

    // staging: chunk = 8 rows x 64 f16 = 1 KB = one global_load_lds per wave.
    // HW writes lane l at chunkbase + 16*l -> row = chunk*8 + (l>>3), phys
    // granule l&7. Source fetches logical granule (l&7) ^ f(row) where
    // f(row) = (row&7) ^ ((row>>4 & 1)<<1) = st_row ^ ((chunk>>1 & 1)<<1).
    const int st_row = lane >> 3;
    const int st_g   = lane & 7;
    const _Float16* Agp = A  + (size_t)row0 * CIN;
    const _Float16* Bgp = Bw + (size_t)col0 * CIN;

    // 32x32x16 fragment addressing: row = lane&31, k = (lane>>5)*8 + j.
    const int rl = lane & 31;
    const int hi = lane >> 5;            // 0/1
    const int h3 = lane & 7;
    const int q4 = (lane >> 4) & 1;      // row bit 4

    // loop-invariant LDS read offsets: logical granule g = s*2+hi of row r
    // lives at physical granule g ^ f(r); f(r) = h3 ^ (q4<<1)
    // (wr*64, m*32 are 0 mod 32 so don't affect row&7 or row bit 4).
    int offA[4][2], offB[4][2];
#pragma unroll
    for (int s = 0; s < 4; ++s)
#pragma unroll
        for (int m = 0; m < 2; ++m) {
            const int pg = ((s * 2 + hi) ^ h3 ^ (q4 << 1)) * 8;
            offA[s][m] = (wr * 64 + m * 32 + rl) * BK + pg;
            offB[s][m] = (wc * 64 + m * 32 + rl) * BK + pg;
        }

#define STAGE(buf, k0) do {                                                    \
    _Pragma("unroll")                                                          \
    for (int j = 0; j < 4; ++j) {                                              \
        const int chunk = wave + j * 4;     /* 16 chunks cover 128 rows */     \
        const int rr = chunk * 8 + st_row;                                     \
        const int sc = (st_g ^ st_row ^ (((chunk >> 1) & 1) << 1)) * 8;        \
        __builtin_amdgcn_global_load_lds(                                      \
            (const __attribute__((address_space(1))) void*)(Agp + (size_t)rr * CIN + (k0) + sc), \
            (__attribute__((address_space(3))) void*)(&As[buf][chunk * 512]),  \
            16, 0, 0);                                                         \
        __builtin_amdgcn_global_load_lds(                                      \
            (const __attribute__((address_space(1))) void*)(Bgp + (size_t)rr * CIN + (k0) + sc), \
            (__attribute__((address_space(3))) void*)(&Bs[buf][chunk * 512]),  \
            16, 0, 0);                                                         \
    } } while (0)

#define COMPUTE(buf) do {                                                      \
    _Pragma("unroll")                                                          \
    for (int s = 0; s < 4; ++s) {                                              \
        f16x8 af0 = *(const f16x8*)(&As[buf][offA[s][0]]);                     \
        f16x8 af1 = *(const f16x8*)(&As[buf][offA[s][1]]);                     \
        f16x8 bf0 = *(const f16x8*)(&Bs[buf][offB[s][0]]);                     \
        f16x8 bf1 = *(const f16x8*)(&Bs[buf][offB[s][1]]);                     \
        __builtin_amdgcn_s_setprio(1);                                         \
        acc[0][0] = __builtin_amdgcn_mfma_f32_32x32x16_f16(af0, bf0, acc[0][0], 0, 0, 0); \
        acc[0][1] = __builtin_amdgcn_mfma_f32_32x32x16_f16(af0, bf1, acc[0][1], 0, 0, 0); \
        acc[1][0] = __builtin_amdgcn_mfma_f32_32x32x16_f16(af1, bf0, acc[1][0], 0, 0, 0); \
        acc[1][1] = __builtin_amdgcn_mfma_f32_32x32x16_f16(af1, bf1, acc[1][1], 0, 0, 0); \
        __builtin_amdgcn_s_setprio(0);                                         \
    } } while (0)

    // prologue
    STAGE(0, 0);
    VMCNT0;
    BARRIER();

#pragma unroll 1
    for (int t = 0; t < NT; t += 2) {
        STAGE(1, (t + 1) * BK);           // prefetch overlaps compute
        COMPUTE(0);
        VMCNT0;                           // drain covered by sibling block
        BARRIER();
        if (t + 2 < NT) STAGE(0, (t + 2) * BK);
        COMPUTE(1);
        if (t + 2 < NT) { VMCNT0; BARRIER(); }
    }

    // epilogue: 32x32 C/D layout: col = lane&31,
    // row = (reg&3) + 8*(reg>>2) + 4*(lane>>5)
#pragma unroll
    for (int m = 0; m < 2; ++m)
#pragma unroll
        for (int n = 0; n < 2; ++n) {
            const int c = col0 + wc * 64 + n * 32 + rl;
            const float tw = term_w[c];
#pragma unroll
            for (int reg = 0; reg < 16; ++reg) {
                const int r = row0 + wr * 64 + m * 32 +
                              (reg & 3) + 8 * (reg >> 2) + 4 * hi;
                C[(size_t)r * COUT + c] = 0.5f * acc[m][n][reg] + term_x[r] + tw;
            }
        }
#undef STAGE
#undef COMPUTE
}

// ---------------------------------------------------------------- launcher
extern "C" void kernel_launch(void* const* d_in, const int* in_sizes, int n_in,
                              void* d_out, int out_size, void* d_ws, size_t ws_size,
                              hipStream_t stream) {
    const float* x      = (const float*)d_in[0];
    const float* weight = (const float*)d_in[1];
    const float* phases = (const float*)d_in[2];
    const float* disks  = (const float*)d_in[3];
    float* out = (float*)d_out;

    char* ws = (char*)d_ws;
    float* pmax   = (float*)(ws);                    // 1 KB
    float* s_tab  = (float*)(ws + 4096);             // 8 KB
    float* dd_tab = (float*)(ws + 16384);            // 8 KB
    float* term_w = (float*)(ws + 32768);            // 8 KB
    float* term_x = (float*)(ws + 49152);            // 16 KB
    _Float16* V   = (_Float16*)(ws + 65536);                               // 8 MB
    _Float16* XQ  = (_Float16*)(ws + 65536 + (size_t)COUT * CIN * 2);      // 16 MB

    prep_a_kernel<<<B_DIM + NMAXBLK + 1, 256, 0, stream>>>(
        x, weight, phases, disks, XQ, term_x, pmax, s_tab, dd_tab);
    prep_b_kernel<<<COUT, 256, 0, stream>>>(weight, pmax, s_tab, dd_tab, V, term_w);
    gemm_kernel<<<(B_DIM / BM) * (COUT / BN), 256, 0, stream>>>(XQ, V, term_x, term_w, out);
}

// Round 9
// 47.943 us; speedup vs baseline: 1.3370x; 1.3344x over previous
//
#include <hip/hip_runtime.h>
#include <hip/hip_bf16.h>
#include <math.h>

#define B_DIM 4096
#define CIN   2048
#define COUT  2048

typedef float f32x4  __attribute__((ext_vector_type(4)));
typedef int   i32x4  __attribute__((ext_vector_type(4)));
typedef int   i32x16 __attribute__((ext_vector_type(16)));
typedef char  c8x8   __attribute__((ext_vector_type(8)));

__device__ inline float wave_reduce_sum(float v) {
#pragma unroll
    for (int off = 32; off > 0; off >>= 1)
        v += __shfl_down(v, off, 64);
    return v;
}
__device__ inline float wave_reduce_max(float v) {
#pragma unroll
    for (int off = 32; off > 0; off >>= 1)
        v = fmaxf(v, __shfl_down(v, off, 64));
    return v;
}

// ---------------------------------------------------------------------------
// Kernel A (fused): blocks [0,4096)   : quantize x -> XQ8 = qx*255-128 (i8,
//                                       exact), term_x
//                   blocks [4096,4352): partial max|weight| -> pmax[256]
//                   block  4352       : s_tab = sin(phi)*(d0+d1), dd_tab,
//                                       smax = max|s|
// ---------------------------------------------------------------------------
#define NMAXBLK 256
__global__ void prep_a_kernel(const float* __restrict__ x,
                              const float* __restrict__ weight,
                              const float* __restrict__ phases,
                              const float* __restrict__ disks,
                              char* __restrict__ XQ8,
                              float* __restrict__ term_x,
                              float* __restrict__ pmax,
                              float* __restrict__ s_tab,
                              float* __restrict__ dd_tab,
                              float* __restrict__ smax_buf) {
    __shared__ float red[4];
    const int blk = blockIdx.x;
    const int tid = threadIdx.x;

    if (blk < B_DIM) {
        // 256 threads x 8 elements = 2048 = CIN, single pass.
        const float* xr = x + (size_t)blk * CIN + tid * 8;
        const f32x4* dk = (const f32x4*)(disks + (size_t)tid * 16);
        f32x4 v0 = ((const f32x4*)xr)[0];
        f32x4 v1 = ((const f32x4*)xr)[1];
        c8x8 h;
        float sum = 0.f;
#pragma unroll
        for (int j = 0; j < 8; ++j) {
            float xv = (j < 4) ? v0[j] : v1[j - 4];
            float qr = rintf(fminf(fmaxf(xv, 0.f), 1.f) * 255.f);  // 0..255
            float q  = qr * (1.f / 255.f);
            f32x4 dv = dk[j >> 1];
            float d0 = dv[(j & 1) * 2], d1 = dv[(j & 1) * 2 + 1];
            sum += q * q * (d0 - d1);
            h[j] = (char)(int)(qr - 128.f);                        // exact i8
        }
        *(c8x8*)(XQ8 + (size_t)blk * CIN + tid * 8) = h;
        sum = wave_reduce_sum(sum);
        if ((tid & 63) == 0) red[tid >> 6] = sum;
        __syncthreads();
        if (tid == 0)
            term_x[blk] = 0.25f * (red[0] + red[1] + red[2] + red[3]);
    } else if (blk < B_DIM + NMAXBLK) {
        const int mb = blk - B_DIM;
        const size_t n4 = (size_t)COUT * CIN / 4;
        const f32x4* w4 = (const f32x4*)weight;
        float m = 0.f;
        for (size_t i = (size_t)mb * 256 + tid; i < n4; i += (size_t)NMAXBLK * 256) {
            f32x4 v = w4[i];
            m = fmaxf(m, fmaxf(fmaxf(fabsf(v[0]), fabsf(v[1])),
                               fmaxf(fabsf(v[2]), fabsf(v[3]))));
        }
        m = wave_reduce_max(m);
        if ((tid & 63) == 0) red[tid >> 6] = m;
        __syncthreads();
        if (tid == 0)
            pmax[mb] = fmaxf(fmaxf(red[0], red[1]), fmaxf(red[2], red[3]));
    } else {
        float lmax = 0.f;
        for (int i = tid; i < CIN; i += 256) {
            float d0 = disks[2 * i], d1 = disks[2 * i + 1];
            float s  = sinf(phases[i]) * (d0 + d1);
            s_tab[i]  = s;
            dd_tab[i] = d0 - d1;
            lmax = fmaxf(lmax, fabsf(s));
        }
        lmax = wave_reduce_max(lmax);
        if ((tid & 63) == 0) red[tid >> 6] = lmax;
        __syncthreads();
        if (tid == 0)
            smax_buf[0] = fmaxf(fmaxf(fmaxf(red[0], red[1]),
                                      fmaxf(red[2], red[3])), 1e-20f);
    }
}

// ---------------------------------------------------------------------------
// Kernel B: V8[o][k] = round(wq * s_k * 127/smax) (i8); term_w2 folds both
// the dd-sum and the +128*Sum(B') correction from the A-shift.
// cross = (smax/(255*127)) * (Sum A'B' + 128*Sum B')
// ---------------------------------------------------------------------------
__global__ void prep_b_kernel(const float* __restrict__ weight,
                              const float* __restrict__ pmax,
                              const float* __restrict__ s_tab,
                              const float* __restrict__ dd_tab,
                              const float* __restrict__ smax_buf,
                              char* __restrict__ V8,
                              float* __restrict__ term_w2) {
    __shared__ float red[4];
    __shared__ float bmax;
    const int tid = threadIdx.x;

    float m = pmax[tid];
    m = wave_reduce_max(m);
    if ((tid & 63) == 0) red[tid >> 6] = m;
    __syncthreads();
    if (tid == 0)
        bmax = tanhf(fmaxf(fmaxf(red[0], red[1]), fmaxf(red[2], red[3])));
    __syncthreads();
    const float inv2m = 0.5f / bmax;             // max|tanh(W)| = tanh(max|W|)
    const float smax  = smax_buf[0];
    const float k127  = 127.f / smax;

    const int o = blockIdx.x;
    const float* wr  = weight + (size_t)o * CIN + tid * 8;
    const f32x4* w4  = (const f32x4*)wr;
    const f32x4* s4  = (const f32x4*)(s_tab  + tid * 8);
    const f32x4* dd4 = (const f32x4*)(dd_tab + tid * 8);
    float sumdd = 0.f, sb = 0.f;
    c8x8 h;
#pragma unroll
    for (int half = 0; half < 2; ++half) {
        f32x4 wv = w4[half], sv = s4[half], ddv = dd4[half];
#pragma unroll
        for (int j = 0; j < 4; ++j) {
            float t  = tanhf(wv[j]);
            float wq = rintf((t * inv2m + 0.5f) * 255.f) * (1.f / 255.f);
            sumdd += wq * wq * ddv[j];
            float bp = rintf(wq * sv[j] * k127);   // [-127,127]
            sb += bp;
            h[half * 4 + j] = (char)(int)bp;
        }
    }
    *(c8x8*)(V8 + (size_t)o * CIN + tid * 8) = h;

    sumdd = wave_reduce_sum(sumdd);
    sb    = wave_reduce_sum(sb);
    if ((tid & 63) == 0) red[tid >> 6] = sumdd;
    __syncthreads();
    float sumdd_t = red[0] + red[1] + red[2] + red[3];
    __syncthreads();
    if ((tid & 63) == 0) red[tid >> 6] = sb;
    __syncthreads();
    if (tid == 0) {
        float sb_t = red[0] + red[1] + red[2] + red[3];
        term_w2[o] = 0.25f * sumdd_t + (64.f * smax / 32385.f) * sb_t;
    }
}

// ---------------------------------------------------------------------------
// Kernel C: i8 GEMM.  acc = Sum A'[b][k]*B'[o][k] (i32, exact);
// out = coef*acc + term_x[b] + term_w2[o],  coef = 0.5*smax/(255*127).
// r5-proven structure: BM=256 BN=128, BK=128 BYTES (NT=16), 8 waves (4Mx2N,
// 64x64/wave as 2x2 of mfma_i32_32x32x32_i8), TRIPLE-buffered LDS (144 KB),
// 6 loads/wave/tile, counted vmcnt(6) + ONE barrier per tile, setprio.
// XOR-granule swizzle both-sides (16B granules, 8/row): phys = logical ^
// f(row), f(r) = (r&7) ^ (((r>>4)&1)<<1). XCD supertile swizzle (r6-verified
// FETCH halving): 4x8 tile rect per XCD.
// ---------------------------------------------------------------------------
#define BM 256
#define BN 128
#define BKB 128                 // K-tile in bytes (= 128 i8)
#define NT (CIN / BKB)          // 16

#define MEMFENCE asm volatile("" ::: "memory")
#define BARRIER() do { MEMFENCE; __builtin_amdgcn_s_barrier(); MEMFENCE; } while (0)
#define VMCNT(N) asm volatile("s_waitcnt vmcnt(" #N ")" ::: "memory")

__global__ __launch_bounds__(512, 2) void
gemm_kernel(const char* __restrict__ A,    // [B_DIM][CIN] i8 (qx*255-128)
            const char* __restrict__ Bw,   // [COUT][CIN] i8 (B')
            const float* __restrict__ term_x,
            const float* __restrict__ term_w2,
            const float* __restrict__ smax_buf,
            float* __restrict__ C) {
    __shared__ __align__(16) char As[3][BM * BKB];  // 3 x 32 KB
    __shared__ __align__(16) char Bs[3][BN * BKB];  // 3 x 16 KB

    const int tid  = threadIdx.x;
    const int wave = tid >> 6;
    const int lane = tid & 63;

    // XCD supertile: grid 256, xcd = wg&7 owns a 4x8 tile rectangle.
    const int wg  = blockIdx.x;
    const int xcd = wg & 7;
    const int idx = wg >> 3;                          // 0..31
    const int tile_m = (xcd >> 1) * 4 + (idx >> 3);   // 0..15
    const int tile_n = (xcd & 1) * 8 + (idx & 7);     // 0..15
    const int row0 = tile_m * BM;
    const int col0 = tile_n * BN;
    const int wr = wave >> 1;   // 0..3 (M)
    const int wc = wave & 1;    // 0..1 (N)

    i32x16 acc[2][2];
#pragma unroll
    for (int m = 0; m < 2; ++m)
#pragma unroll
        for (int n = 0; n < 2; ++n)
#pragma unroll
            for (int j = 0; j < 16; ++j)
                acc[m][n][j] = 0;

    // staging: chunk = 8 rows x 128 B = 1 KB = one global_load_lds per wave.
    // HW: lane l -> row chunk*8 + (l>>3), phys granule l&7 (16B). Source
    // fetches logical granule (l&7) ^ f(row); f(row) = st_row ^ ((chunk>>1&1)<<1).
    const int st_row = lane >> 3;
    const int st_g   = lane & 7;
    const char* Agp = A  + (size_t)row0 * CIN;
    const char* Bgp = Bw + (size_t)col0 * CIN;

    // fragment addressing (32x32x32 i8): row = lane&31, 16 contiguous k at
    // k = (lane>>5)*16; per k-slice ks (32 k), logical granule = ks*2 + hi.
    const int rl = lane & 31;
    const int hi = lane >> 5;
    const int fxor = (rl & 7) ^ (((rl >> 4) & 1) << 1);   // f(row), row%32==rl%32

    int offA[4][2], offB[4][2];
#pragma unroll
    for (int ks = 0; ks < 4; ++ks)
#pragma unroll
        for (int m = 0; m < 2; ++m) {
            const int pg = ((ks * 2 + hi) ^ fxor) * 16;
            offA[ks][m] = (wr * 64 + m * 32 + rl) * BKB + pg;
            offB[ks][m] = (wc * 64 + m * 32 + rl) * BKB + pg;
        }

#define STAGE(buf, k0) do {                                                    \
    _Pragma("unroll")                                                          \
    for (int j = 0; j < 4; ++j) {        /* A: 32 chunks = 256 rows */         \
        const int chunk = wave + j * 8;                                        \
        const int rr = chunk * 8 + st_row;                                     \
        const int sc = (st_g ^ st_row ^ (((chunk >> 1) & 1) << 1)) * 16;       \
        __builtin_amdgcn_global_load_lds(                                      \
            (const __attribute__((address_space(1))) void*)(Agp + (size_t)rr * CIN + (k0) + sc), \
            (__attribute__((address_space(3))) void*)(&As[buf][chunk * 1024]), \
            16, 0, 0);                                                         \
    }                                                                          \
    _Pragma("unroll")                                                          \
    for (int j = 0; j < 2; ++j) {        /* B: 16 chunks = 128 rows */         \
        const int chunk = wave + j * 8;                                        \
        const int rr = chunk * 8 + st_row;                                     \
        const int sc = (st_g ^ st_row ^ (((chunk >> 1) & 1) << 1)) * 16;       \
        __builtin_amdgcn_global_load_lds(                                      \
            (const __attribute__((address_space(1))) void*)(Bgp + (size_t)rr * CIN + (k0) + sc), \
            (__attribute__((address_space(3))) void*)(&Bs[buf][chunk * 1024]), \
            16, 0, 0);                                                         \
    } } while (0)

#define TILE(bufc, STAGE_STMT, VM_STMT) do {                                   \
    STAGE_STMT;                                                                \
    _Pragma("unroll")                                                          \
    for (int ks = 0; ks < 4; ++ks) {                                           \
        i32x4 a0 = *(const i32x4*)(&As[bufc][offA[ks][0]]);                    \
        i32x4 a1 = *(const i32x4*)(&As[bufc][offA[ks][1]]);                    \
        i32x4 b0 = *(const i32x4*)(&Bs[bufc][offB[ks][0]]);                    \
        i32x4 b1 = *(const i32x4*)(&Bs[bufc][offB[ks][1]]);                    \
        __builtin_amdgcn_s_setprio(1);                                         \
        acc[0][0] = __builtin_amdgcn_mfma_i32_32x32x32_i8(a0, b0, acc[0][0], 0, 0, 0); \
        acc[0][1] = __builtin_amdgcn_mfma_i32_32x32x32_i8(a0, b1, acc[0][1], 0, 0, 0); \
        acc[1][0] = __builtin_amdgcn_mfma_i32_32x32x32_i8(a1, b0, acc[1][0], 0, 0, 0); \
        acc[1][1] = __builtin_amdgcn_mfma_i32_32x32x32_i8(a1, b1, acc[1][1], 0, 0, 0); \
        __builtin_amdgcn_s_setprio(0);                                         \
    }                                                                          \
    VM_STMT;                                                                   \
    BARRIER();                                                                 \
} while (0)

    // prologue: stage tiles 0,1 (6 loads each)
    STAGE(0, 0);
    STAGE(1, BKB);
    VMCNT(6);
    BARRIER();

    int k0 = 0;
#pragma unroll 1
    for (int grp = 0; grp < 4; ++grp) {           // tiles 0..11
        TILE(0, STAGE(2, k0 + 2 * BKB), VMCNT(6));
        TILE(1, STAGE(0, k0 + 3 * BKB), VMCNT(6));
        TILE(2, STAGE(1, k0 + 4 * BKB), VMCNT(6));
        k0 += 3 * BKB;
    }
    // tail: tiles 12(buf0),13(buf1),14(buf2),15(buf0)
    TILE(0, STAGE(2, 14 * BKB), VMCNT(6));
    TILE(1, STAGE(0, 15 * BKB), VMCNT(6));
    TILE(2, (void)0, VMCNT(0));
    TILE(0, (void)0, (void)0);

    // epilogue: 32x32 C/D layout (dtype-independent): col = lane&31,
    // row = (reg&3) + 8*(reg>>2) + 4*(lane>>5)
    const float coef = 0.5f * smax_buf[0] / 32385.f;   // smax/(255*127)*0.5
#pragma unroll
    for (int m = 0; m < 2; ++m)
#pragma unroll
        for (int n = 0; n < 2; ++n) {
            const int c = col0 + wc * 64 + n * 32 + rl;
            const float tw = term_w2[c];
#pragma unroll
            for (int reg = 0; reg < 16; ++reg) {
                const int r = row0 + wr * 64 + m * 32 +
                              (reg & 3) + 8 * (reg >> 2) + 4 * hi;
                C[(size_t)r * COUT + c] =
                    coef * (float)acc[m][n][reg] + term_x[r] + tw;
            }
        }
#undef STAGE
#undef TILE
}

// ---------------------------------------------------------------- launcher
extern "C" void kernel_launch(void* const* d_in, const int* in_sizes, int n_in,
                              void* d_out, int out_size, void* d_ws, size_t ws_size,
                              hipStream_t stream) {
    const float* x      = (const float*)d_in[0];
    const float* weight = (const float*)d_in[1];
    const float* phases = (const float*)d_in[2];
    const float* disks  = (const float*)d_in[3];
    float* out = (float*)d_out;

    char* ws = (char*)d_ws;
    float* pmax     = (float*)(ws);                  // 1 KB
    float* smax_buf = (float*)(ws + 1024);           // 4 B
    float* s_tab    = (float*)(ws + 4096);           // 8 KB
    float* dd_tab   = (float*)(ws + 16384);          // 8 KB
    float* term_w2  = (float*)(ws + 32768);          // 8 KB
    float* term_x   = (float*)(ws + 49152);          // 16 KB
    char* XQ8 = (char*)(ws + 65536);                               // 8 MB
    char* V8  = (char*)(ws + 65536 + (size_t)B_DIM * CIN);         // 4 MB

    prep_a_kernel<<<B_DIM + NMAXBLK + 1, 256, 0, stream>>>(
        x, weight, phases, disks, XQ8, term_x, pmax, s_tab, dd_tab, smax_buf);
    prep_b_kernel<<<COUT, 256, 0, stream>>>(
        weight, pmax, s_tab, dd_tab, smax_buf, V8, term_w2);
    gemm_kernel<<<(B_DIM / BM) * (COUT / BN), 512, 0, stream>>>(
        XQ8, V8, term_x, term_w2, smax_buf, out);
}